// Round 1
// baseline (2049.878 us; speedup 1.0000x reference)
//
#include <hip/hip_runtime.h>
#include <hip/hip_bf16.h>
#include <stdint.h>

// ---------------------------------------------------------------------------
// Swin-V2 block, MI355X. Stages:
//  cvt weights -> bf16 | cpb table | bias fill
//  LN1+shift+window-partition -> xw(bf16)
//  GEMM qkv (bf16 MFMA) -> qkv(bf16)
//  attention per (window,head) (f32 VALU) -> attn(bf16)
//  GEMM proj + window-reverse + residual -> d_out(f32)
//  LN2 -> xn2(bf16)
//  GEMM w12 (SwiGLU epilogue) -> h(bf16)
//  GEMM w3 + residual -> d_out(f32)
// ---------------------------------------------------------------------------

typedef __attribute__((ext_vector_type(8))) short bf16x8;
typedef __attribute__((ext_vector_type(4))) float f32x4;

__device__ __forceinline__ float bf2f(unsigned int u) {
  unsigned int v = u << 16;
  float f;
  __builtin_memcpy(&f, &v, 4);
  return f;
}
__device__ __forceinline__ unsigned short f2bf(float f) {
  unsigned int x;
  __builtin_memcpy(&x, &f, 4);
  unsigned int r = x + 0x7fffu + ((x >> 16) & 1u);
  return (unsigned short)(r >> 16);
}

__device__ __forceinline__ void gload16(const unsigned short* g, short* l) {
  __builtin_amdgcn_global_load_lds((const __attribute__((address_space(1))) char*)g,
                                   (__attribute__((address_space(3))) char*)l,
                                   16, 0, 0);
}

// ---------------- small prep kernels ----------------

__global__ void cvt_bf16_kernel(const float* __restrict__ in,
                                unsigned short* __restrict__ out, int n) {
  int i = blockIdx.x * 256 + threadIdx.x;
  if (i < n) out[i] = f2bf(in[i]);
}

// reorder w12 rows so that 16-row groups alternate x1/x2: out row n (g=n>>4,m=n&15):
// g even -> w1 row (g>>1)*16+m ; g odd -> w2 row (g>>1)*16+m
__global__ void w12_reorder_kernel(const float* __restrict__ in,
                                   unsigned short* __restrict__ out) {
  int i = blockIdx.x * 256 + threadIdx.x;  // exactly 3072*384
  int n = i / 384, k = i - n * 384;
  int g = n >> 4, m = n & 15;
  int src = (g & 1) ? (1536 + (g >> 1) * 16 + m) : ((g >> 1) * 16 + m);
  out[i] = f2bf(in[src * 384 + k]);
}

// CPB MLP: 225 coord rows -> relu(w1 x + b1) (512) -> w2 -> (225,12)
__global__ void cpb_table_kernel(const float* __restrict__ w1,
                                 const float* __restrict__ b1,
                                 const float* __restrict__ w2,
                                 float* __restrict__ tbl) {
  int r = threadIdx.x;
  if (r >= 225) return;
  int a = r / 15, c = r - a * 15;
  float fy = (float)(a - 7) * (8.0f / 7.0f);
  float fx = (float)(c - 7) * (8.0f / 7.0f);
  float sy = (fy > 0.f) ? 1.f : ((fy < 0.f) ? -1.f : 0.f);
  float sx = (fx > 0.f) ? 1.f : ((fx < 0.f) ? -1.f : 0.f);
  float t0 = sy * log2f(fabsf(fy) + 1.f) * (1.0f / 3.0f);
  float t1 = sx * log2f(fabsf(fx) + 1.f) * (1.0f / 3.0f);
  float acc[12];
#pragma unroll
  for (int h = 0; h < 12; ++h) acc[h] = 0.f;
  for (int j = 0; j < 512; ++j) {
    float hj = w1[j * 2] * t0 + w1[j * 2 + 1] * t1 + b1[j];
    hj = fmaxf(hj, 0.f);
#pragma unroll
    for (int h = 0; h < 12; ++h) acc[h] += w2[h * 512 + j] * hj;
  }
#pragma unroll
  for (int h = 0; h < 12; ++h) tbl[r * 12 + h] = acc[h];
}

// bias[h][i][j] = tbl[rpi(i,j)][h], rpi = (dy+7)*15 + (dx+7)
__global__ void bias_fill_kernel(const float* __restrict__ tbl,
                                 float* __restrict__ bias) {
  int idx = blockIdx.x * 256 + threadIdx.x;  // exactly 12*4096
  int h = idx >> 12, ij = idx & 4095;
  int i = ij >> 6, j = ij & 63;
  int dy = (i >> 3) - (j >> 3) + 7;
  int dx = (i & 7) - (j & 7) + 7;
  bias[idx] = tbl[(dy * 15 + dx) * 12 + h];
}

// ---------------- LayerNorm (+ optional shift/window scatter) ----------------
// one wave per token (C=384 = 6 elems/lane)
__global__ __launch_bounds__(256) void ln_kernel(const float* __restrict__ xin,
                                                 const float* __restrict__ g,
                                                 const float* __restrict__ b,
                                                 unsigned short* __restrict__ outw,
                                                 int shift_mode) {
  int wid = threadIdx.x >> 6, lane = threadIdx.x & 63;
  int t = blockIdx.x * 4 + wid;
  const float* xp = xin + (size_t)t * 384;
  float v[6];
  float s = 0.f, sq = 0.f;
#pragma unroll
  for (int i = 0; i < 6; ++i) {
    v[i] = xp[lane + i * 64];
    s += v[i];
    sq += v[i] * v[i];
  }
#pragma unroll
  for (int off = 32; off >= 1; off >>= 1) {
    s += __shfl_xor(s, off);
    sq += __shfl_xor(sq, off);
  }
  float mean = s * (1.f / 384.f);
  float var = sq * (1.f / 384.f) - mean * mean;
  float rstd = rsqrtf(var + 1e-5f);
  int row;
  if (shift_mode) {
    int bb = t >> 12, rem = t & 4095;
    int hh = rem >> 6, ww = rem & 63;
    int hs = (hh + 60) & 63, wsd = (ww + 60) & 63;  // roll(-4,-4)
    row = bb * 4096 + ((hs >> 3) * 8 + (wsd >> 3)) * 64 + (hs & 7) * 8 + (wsd & 7);
  } else {
    row = t;
  }
  unsigned short* op = outw + (size_t)row * 384;
#pragma unroll
  for (int i = 0; i < 6; ++i) {
    int c = lane + i * 64;
    op[c] = f2bf((v[i] - mean) * rstd * g[c] + b[c]);
  }
}

// ---------------- bf16 MFMA GEMM: C = A(MxK) * B(NxK)^T ----------------
// 128x128 tile, BK=64, 4 waves (2x2 of 64x64), 16x16x32 MFMA.
// MODE 0: qkv  -> bf16 out[row*N+col] + cbias
// MODE 1: proj -> f32 d_out at window-reversed+rolled index, + cbias + shortcut
// MODE 2: ffn1 -> SwiGLU pairing (cols interleaved by 16-groups), bf16 h[row*1536+hidx]
// MODE 3: ffn2 -> f32 d_out[row*384+col] += acc + cbias (residual RMW)
template <int MODE>
__global__ __launch_bounds__(256, 2) void gemm_bt(
    const unsigned short* __restrict__ A, const unsigned short* __restrict__ B,
    const float* __restrict__ cbias, unsigned short* __restrict__ outB,
    float* __restrict__ outF, const float* __restrict__ shortcut, int N, int K) {
  __shared__ short As[128][64];
  __shared__ short Bs[128][64];
  int tid = threadIdx.x, wid = tid >> 6, lane = tid & 63;
  int tn = blockIdx.x, tm = blockIdx.y;

  const unsigned short* aSrc =
      A + (size_t)(tm * 128 + wid * 32 + (lane >> 3)) * K + (lane & 7) * 8;
  const unsigned short* bSrc =
      B + (size_t)(tn * 128 + wid * 32 + (lane >> 3)) * K + (lane & 7) * 8;

  f32x4 acc[4][4];
#pragma unroll
  for (int a = 0; a < 4; ++a)
#pragma unroll
    for (int b2 = 0; b2 < 4; ++b2) acc[a][b2] = (f32x4){0.f, 0.f, 0.f, 0.f};

  int wm = (wid >> 1) * 64, wn = (wid & 1) * 64;
  int lr = lane & 15, lk = lane >> 4;
  int nk = K >> 6;

  for (int kt = 0; kt < nk; ++kt) {
#pragma unroll
    for (int t = 0; t < 4; ++t) {
      gload16(aSrc + (size_t)(t * 8) * K + kt * 64, &As[wid * 32 + t * 8][0]);
      gload16(bSrc + (size_t)(t * 8) * K + kt * 64, &Bs[wid * 32 + t * 8][0]);
    }
    __syncthreads();
#pragma unroll
    for (int kk = 0; kk < 2; ++kk) {
      bf16x8 af[4], bfr[4];
#pragma unroll
      for (int mi = 0; mi < 4; ++mi)
        af[mi] = *(const bf16x8*)&As[wm + mi * 16 + lr][kk * 32 + lk * 8];
#pragma unroll
      for (int ni = 0; ni < 4; ++ni)
        bfr[ni] = *(const bf16x8*)&Bs[wn + ni * 16 + lr][kk * 32 + lk * 8];
#pragma unroll
      for (int mi = 0; mi < 4; ++mi)
#pragma unroll
        for (int ni = 0; ni < 4; ++ni)
          acc[mi][ni] =
              __builtin_amdgcn_mfma_f32_16x16x32_bf16(af[mi], bfr[ni], acc[mi][ni], 0, 0, 0);
    }
    __syncthreads();
  }

  int row0 = tm * 128 + wm + lk * 4;
  int col0 = tn * 128 + wn + lr;
#pragma unroll
  for (int mi = 0; mi < 4; ++mi) {
    if (MODE == 2) {
#pragma unroll
      for (int ni = 0; ni < 4; ni += 2) {
        int colE = col0 + ni * 16;                 // even 16-group (x1)
        int hidx = ((colE >> 5) << 4) + lr;        // hidden index in [0,1536)
        float b1v = cbias[hidx];
        float b2v = cbias[1536 + hidx];
#pragma unroll
        for (int reg = 0; reg < 4; ++reg) {
          int row = row0 + mi * 16 + reg;
          float x1 = acc[mi][ni][reg] + b1v;
          float x2 = acc[mi][ni + 1][reg] + b2v;
          float hv = x1 * x2 / (1.f + __expf(-x2));  // x1 * silu(x2)
          outB[(size_t)row * 1536 + hidx] = f2bf(hv);
        }
      }
    } else {
#pragma unroll
      for (int ni = 0; ni < 4; ++ni) {
        int col = col0 + ni * 16;
        float bv = cbias[col];
#pragma unroll
        for (int reg = 0; reg < 4; ++reg) {
          int row = row0 + mi * 16 + reg;
          float v = acc[mi][ni][reg] + bv;
          if (MODE == 0) {
            outB[(size_t)row * N + col] = f2bf(v);
          } else if (MODE == 1) {
            int win = row >> 6, n = row & 63;
            int bb = win >> 6, wd = win & 63;
            int hh = (((wd >> 3) << 3) + (n >> 3) + 4) & 63;  // un-roll(+4)
            int ww2 = (((wd & 7) << 3) + (n & 7) + 4) & 63;
            size_t idx = ((size_t)(bb << 12) + hh * 64 + ww2) * 384 + col;
            outF[idx] = v + shortcut[idx];
          } else {  // MODE 3
            size_t idx = (size_t)row * 384 + col;
            outF[idx] = v + outF[idx];
          }
        }
      }
    }
  }
}

// ---------------- attention: one block per (window, head) ----------------
__global__ __launch_bounds__(256) void attn_kernel(
    const unsigned short* __restrict__ qkv, const float* __restrict__ logit_scale,
    const float* __restrict__ bias, unsigned short* __restrict__ outw) {
  __shared__ float qs[64][33];
  __shared__ float ks[64][33];
  __shared__ float vs[64][33];
  __shared__ float S[64][65];
  int head = blockIdx.x, win = blockIdx.y;
  int tid = threadIdx.x;
  int r = tid >> 2, d0 = (tid & 3) << 3;

  {
    const unsigned short* bp = qkv + (size_t)(win * 64 + r) * 1152 + head * 32 + d0;
    uint4 uq = *(const uint4*)(bp);
    uint4 uk = *(const uint4*)(bp + 384);
    uint4 uv = *(const uint4*)(bp + 768);
    unsigned int aq[4] = {uq.x, uq.y, uq.z, uq.w};
    unsigned int ak[4] = {uk.x, uk.y, uk.z, uk.w};
    unsigned int av[4] = {uv.x, uv.y, uv.z, uv.w};
#pragma unroll
    for (int e = 0; e < 4; ++e) {
      qs[r][d0 + 2 * e] = bf2f(aq[e] & 0xffffu);
      qs[r][d0 + 2 * e + 1] = bf2f(aq[e] >> 16);
      ks[r][d0 + 2 * e] = bf2f(ak[e] & 0xffffu);
      ks[r][d0 + 2 * e + 1] = bf2f(ak[e] >> 16);
      vs[r][d0 + 2 * e] = bf2f(av[e] & 0xffffu);
      vs[r][d0 + 2 * e + 1] = bf2f(av[e] >> 16);
    }
  }
  __syncthreads();

  if (tid < 128) {
    int rr = tid & 63;
    float* arr = (tid < 64) ? qs[rr] : ks[rr];
    float ssum = 0.f;
#pragma unroll
    for (int d = 0; d < 32; ++d) ssum += arr[d] * arr[d];
    float sc = 1.f / fmaxf(sqrtf(ssum), 1e-12f);
    if (tid < 64) sc *= __expf(fminf(logit_scale[head], 4.6051702f));
#pragma unroll
    for (int d = 0; d < 32; ++d) arr[d] *= sc;
  }
  __syncthreads();

  int i = tid >> 2, jg = tid & 3;
  int wd = win & 63, wh = wd >> 3, ww = wd & 7;
  int hi = (wh << 3) + (i >> 3), wi = (ww << 3) + (i & 7);
  int regi = (hi < 56 ? 0 : (hi < 60 ? 1 : 2)) * 3 + (wi < 56 ? 0 : (wi < 60 ? 1 : 2));

  float qf[32];
#pragma unroll
  for (int d = 0; d < 32; ++d) qf[d] = qs[i][d];

  float sv[16];
  const float* bp2 = bias + ((size_t)head * 64 + i) * 64;
#pragma unroll 4
  for (int jj = 0; jj < 16; ++jj) {
    int j = (jg << 4) + jj;
    float dot = 0.f;
#pragma unroll
    for (int d = 0; d < 32; ++d) dot += qf[d] * ks[j][d];
    int hj = (wh << 3) + (j >> 3), wj = (ww << 3) + (j & 7);
    int regj = (hj < 56 ? 0 : (hj < 60 ? 1 : 2)) * 3 + (wj < 56 ? 0 : (wj < 60 ? 1 : 2));
    sv[jj] = dot + bp2[j] + (regi != regj ? -1e30f : 0.f);
  }
  float m = sv[0];
#pragma unroll
  for (int jj = 1; jj < 16; ++jj) m = fmaxf(m, sv[jj]);
  m = fmaxf(m, __shfl_xor(m, 1));
  m = fmaxf(m, __shfl_xor(m, 2));
  float ssum = 0.f;
#pragma unroll
  for (int jj = 0; jj < 16; ++jj) {
    sv[jj] = __expf(sv[jj] - m);
    ssum += sv[jj];
  }
  ssum += __shfl_xor(ssum, 1);
  ssum += __shfl_xor(ssum, 2);
  float inv = 1.f / ssum;
#pragma unroll
  for (int jj = 0; jj < 16; ++jj) S[i][(jg << 4) + jj] = sv[jj] * inv;
  __syncthreads();

  float o[8];
#pragma unroll
  for (int e = 0; e < 8; ++e) o[e] = 0.f;
  for (int j = 0; j < 64; ++j) {
    float p = S[i][j];
#pragma unroll
    for (int e = 0; e < 8; ++e) o[e] += p * vs[j][d0 + e];
  }
  unsigned int p0 = (unsigned)f2bf(o[0]) | ((unsigned)f2bf(o[1]) << 16);
  unsigned int p1 = (unsigned)f2bf(o[2]) | ((unsigned)f2bf(o[3]) << 16);
  unsigned int p2 = (unsigned)f2bf(o[4]) | ((unsigned)f2bf(o[5]) << 16);
  unsigned int p3 = (unsigned)f2bf(o[6]) | ((unsigned)f2bf(o[7]) << 16);
  uint4 u = {p0, p1, p2, p3};
  *(uint4*)&outw[(size_t)(win * 64 + i) * 384 + head * 32 + d0] = u;
}

// ---------------------------------------------------------------------------

extern "C" void kernel_launch(void* const* d_in, const int* in_sizes, int n_in,
                              void* d_out, int out_size, void* d_ws, size_t ws_size,
                              hipStream_t stream) {
  const float* x = (const float*)d_in[0];
  const float* n1g = (const float*)d_in[3];
  const float* n1b = (const float*)d_in[4];
  const float* qkv_w = (const float*)d_in[5];
  const float* qkv_b = (const float*)d_in[6];
  const float* proj_w = (const float*)d_in[7];
  const float* proj_b = (const float*)d_in[8];
  const float* cpb_w1 = (const float*)d_in[9];
  const float* cpb_b1 = (const float*)d_in[10];
  const float* cpb_w2 = (const float*)d_in[11];
  const float* lscale = (const float*)d_in[12];
  const float* n2g = (const float*)d_in[13];
  const float* n2b = (const float*)d_in[14];
  const float* w12_w = (const float*)d_in[15];
  const float* w12_b = (const float*)d_in[16];
  const float* w3_w = (const float*)d_in[17];
  const float* w3_b = (const float*)d_in[18];
  float* outF = (float*)d_out;
  char* ws = (char*)d_ws;

  // workspace layout (bytes)
  unsigned short* xw = (unsigned short*)(ws + 0ull);             // 100663296
  unsigned short* qkvb = (unsigned short*)(ws + 100663296ull);   // 301989888
  unsigned short* attn = (unsigned short*)(ws + 402653184ull);   // 100663296 (later xn2)
  unsigned short* xn2 = attn;
  unsigned short* hbuf = (unsigned short*)(ws + 0ull);           // reuse xw+qkv region
  char* wbase = ws + 503316480ull;
  unsigned short* wqkv = (unsigned short*)(wbase);                         // 884736
  unsigned short* wproj = (unsigned short*)(wbase + 884736ull);            // 294912
  unsigned short* w12r = (unsigned short*)(wbase + 1179648ull);            // 2359296
  unsigned short* w3b = (unsigned short*)(wbase + 3538944ull);             // 1179648
  float* tbl = (float*)(wbase + 4718592ull);                               // 10816
  float* bias = (float*)(wbase + 4729408ull);                              // 196608

  cvt_bf16_kernel<<<1728, 256, 0, stream>>>(qkv_w, wqkv, 442368);
  cvt_bf16_kernel<<<576, 256, 0, stream>>>(proj_w, wproj, 147456);
  cvt_bf16_kernel<<<2304, 256, 0, stream>>>(w3_w, w3b, 589824);
  w12_reorder_kernel<<<4608, 256, 0, stream>>>(w12_w, w12r);
  cpb_table_kernel<<<1, 256, 0, stream>>>(cpb_w1, cpb_b1, cpb_w2, tbl);
  bias_fill_kernel<<<192, 256, 0, stream>>>(tbl, bias);

  ln_kernel<<<32768, 256, 0, stream>>>(x, n1g, n1b, xw, 1);
  gemm_bt<0><<<dim3(9, 1024), 256, 0, stream>>>(xw, wqkv, qkv_b, qkvb, nullptr, nullptr,
                                                1152, 384);
  attn_kernel<<<dim3(12, 2048), 256, 0, stream>>>(qkvb, lscale, bias, attn);
  gemm_bt<1><<<dim3(3, 1024), 256, 0, stream>>>(attn, wproj, proj_b, nullptr, outF, x,
                                                384, 384);
  ln_kernel<<<32768, 256, 0, stream>>>(outF, n2g, n2b, xn2, 0);
  gemm_bt<2><<<dim3(24, 1024), 256, 0, stream>>>(xn2, w12r, w12_b, hbuf, nullptr, nullptr,
                                                 3072, 384);
  gemm_bt<3><<<dim3(3, 1024), 256, 0, stream>>>(hbuf, w3b, w3_b, nullptr, outF, nullptr,
                                                384, 1536);
}

// Round 2
// 1739.193 us; speedup vs baseline: 1.1786x; 1.1786x over previous
//
#include <hip/hip_runtime.h>
#include <hip/hip_bf16.h>
#include <stdint.h>

// ---------------------------------------------------------------------------
// Swin-V2 block, MI355X.
//  cvt weights -> bf16 | cpb table | bias fill (register-fragment order)
//  LN1+shift+window-partition -> xw(bf16)
//  GEMM qkv -> qk[token][768](bf16) + vt[head][win][32][64](bf16)
//  attention: 1 wave per (win,head), MFMA QK^T + in-reg softmax + MFMA PV
//  GEMM proj + window-reverse + residual -> d_out(f32)
//  LN2 -> xn2(bf16)
//  GEMM w12 (SwiGLU epilogue) -> h(bf16)
//  GEMM w3 + residual -> d_out(f32)
// ---------------------------------------------------------------------------

typedef __attribute__((ext_vector_type(8))) short bf16x8;
typedef __attribute__((ext_vector_type(4))) float f32x4;

__device__ __forceinline__ float bf2f(unsigned int u) {
  unsigned int v = u << 16;
  float f;
  __builtin_memcpy(&f, &v, 4);
  return f;
}
__device__ __forceinline__ unsigned short f2bf(float f) {
  unsigned int x;
  __builtin_memcpy(&x, &f, 4);
  unsigned int r = x + 0x7fffu + ((x >> 16) & 1u);
  return (unsigned short)(r >> 16);
}
__device__ __forceinline__ bf16x8 as_bf(uint4 u) {
  bf16x8 b;
  __builtin_memcpy(&b, &u, 16);
  return b;
}

__device__ __forceinline__ void gload16(const unsigned short* g, short* l) {
  __builtin_amdgcn_global_load_lds((const __attribute__((address_space(1))) char*)g,
                                   (__attribute__((address_space(3))) char*)l,
                                   16, 0, 0);
}

// ---------------- small prep kernels ----------------

__global__ void cvt_bf16_kernel(const float* __restrict__ in,
                                unsigned short* __restrict__ out, int n) {
  int i = blockIdx.x * 256 + threadIdx.x;
  if (i < n) out[i] = f2bf(in[i]);
}

__global__ void w12_reorder_kernel(const float* __restrict__ in,
                                   unsigned short* __restrict__ out) {
  int i = blockIdx.x * 256 + threadIdx.x;  // exactly 3072*384
  int n = i / 384, k = i - n * 384;
  int g = n >> 4, m = n & 15;
  int src = (g & 1) ? (1536 + (g >> 1) * 16 + m) : ((g >> 1) * 16 + m);
  out[i] = f2bf(in[src * 384 + k]);
}

__global__ void cpb_table_kernel(const float* __restrict__ w1,
                                 const float* __restrict__ b1,
                                 const float* __restrict__ w2,
                                 float* __restrict__ tbl) {
  int r = threadIdx.x;
  if (r >= 225) return;
  int a = r / 15, c = r - a * 15;
  float fy = (float)(a - 7) * (8.0f / 7.0f);
  float fx = (float)(c - 7) * (8.0f / 7.0f);
  float sy = (fy > 0.f) ? 1.f : ((fy < 0.f) ? -1.f : 0.f);
  float sx = (fx > 0.f) ? 1.f : ((fx < 0.f) ? -1.f : 0.f);
  float t0 = sy * log2f(fabsf(fy) + 1.f) * (1.0f / 3.0f);
  float t1 = sx * log2f(fabsf(fx) + 1.f) * (1.0f / 3.0f);
  float acc[12];
#pragma unroll
  for (int h = 0; h < 12; ++h) acc[h] = 0.f;
  for (int j = 0; j < 512; ++j) {
    float hj = w1[j * 2] * t0 + w1[j * 2 + 1] * t1 + b1[j];
    hj = fmaxf(hj, 0.f);
#pragma unroll
    for (int h = 0; h < 12; ++h) acc[h] += w2[h * 512 + j] * hj;
  }
#pragma unroll
  for (int h = 0; h < 12; ++h) tbl[r * 12 + h] = acc[h];
}

// biasr[head][lane][q] with q = fn*16+fm*4+r  ->  value bias[head][i][j],
// i = (lane&15)+16*fn, j = (lane>>4)*4+r+16*fm  (MFMA S^T register order)
__global__ void bias_fill_kernel(const float* __restrict__ tbl,
                                 float* __restrict__ biasr) {
  int idx = blockIdx.x * 256 + threadIdx.x;  // exactly 12*64*64
  int head = idx >> 12, rem = idx & 4095;
  int lane = rem >> 6, q = rem & 63;
  int fn = q >> 4, fm = (q >> 2) & 3, r = q & 3;
  int i = (lane & 15) + 16 * fn;
  int j = ((lane >> 4) << 2) + r + 16 * fm;
  int dy = (i >> 3) - (j >> 3) + 7;
  int dx = (i & 7) - (j & 7) + 7;
  biasr[idx] = tbl[(dy * 15 + dx) * 12 + head];
}

// ---------------- LayerNorm (+ optional shift/window scatter) ----------------
__global__ __launch_bounds__(256) void ln_kernel(const float* __restrict__ xin,
                                                 const float* __restrict__ g,
                                                 const float* __restrict__ b,
                                                 unsigned short* __restrict__ outw,
                                                 int shift_mode) {
  int wid = threadIdx.x >> 6, lane = threadIdx.x & 63;
  int t = blockIdx.x * 4 + wid;
  const float* xp = xin + (size_t)t * 384;
  float v[6];
  float s = 0.f, sq = 0.f;
#pragma unroll
  for (int i = 0; i < 6; ++i) {
    v[i] = xp[lane + i * 64];
    s += v[i];
    sq += v[i] * v[i];
  }
#pragma unroll
  for (int off = 32; off >= 1; off >>= 1) {
    s += __shfl_xor(s, off);
    sq += __shfl_xor(sq, off);
  }
  float mean = s * (1.f / 384.f);
  float var = sq * (1.f / 384.f) - mean * mean;
  float rstd = rsqrtf(var + 1e-5f);
  int row;
  if (shift_mode) {
    int bb = t >> 12, rem = t & 4095;
    int hh = rem >> 6, ww = rem & 63;
    int hs = (hh + 60) & 63, wsd = (ww + 60) & 63;  // roll(-4,-4)
    row = bb * 4096 + ((hs >> 3) * 8 + (wsd >> 3)) * 64 + (hs & 7) * 8 + (wsd & 7);
  } else {
    row = t;
  }
  unsigned short* op = outw + (size_t)row * 384;
#pragma unroll
  for (int i = 0; i < 6; ++i) {
    int c = lane + i * 64;
    op[c] = f2bf((v[i] - mean) * rstd * g[c] + b[c]);
  }
}

// ---------------- bf16 MFMA GEMM: C = A(MxK) * B(NxK)^T ----------------
// MODE 0: qkv  -> qk[row*768+col] bf16 (col<768) ; V^T -> outB2[head][win][d][n]
// MODE 1: proj -> f32 d_out at window-reversed+rolled index, + cbias + shortcut
// MODE 2: ffn1 -> SwiGLU pairing, bf16 h[row*1536+hidx]
// MODE 3: ffn2 -> f32 d_out[row*384+col] += acc + cbias
template <int MODE>
__global__ __launch_bounds__(256, 2) void gemm_bt(
    const unsigned short* __restrict__ A, const unsigned short* __restrict__ B,
    const float* __restrict__ cbias, unsigned short* __restrict__ outB,
    unsigned short* __restrict__ outB2, float* __restrict__ outF,
    const float* __restrict__ shortcut, int N, int K) {
  __shared__ short As[128][64];
  __shared__ short Bs[128][64];
  int tid = threadIdx.x, wid = tid >> 6, lane = tid & 63;
  int tn = blockIdx.x, tm = blockIdx.y;

  const unsigned short* aSrc =
      A + (size_t)(tm * 128 + wid * 32 + (lane >> 3)) * K + (lane & 7) * 8;
  const unsigned short* bSrc =
      B + (size_t)(tn * 128 + wid * 32 + (lane >> 3)) * K + (lane & 7) * 8;

  f32x4 acc[4][4];
#pragma unroll
  for (int a = 0; a < 4; ++a)
#pragma unroll
    for (int b2 = 0; b2 < 4; ++b2) acc[a][b2] = (f32x4){0.f, 0.f, 0.f, 0.f};

  int wm = (wid >> 1) * 64, wn = (wid & 1) * 64;
  int lr = lane & 15, lk = lane >> 4;
  int nk = K >> 6;

  for (int kt = 0; kt < nk; ++kt) {
#pragma unroll
    for (int t = 0; t < 4; ++t) {
      gload16(aSrc + (size_t)(t * 8) * K + kt * 64, &As[wid * 32 + t * 8][0]);
      gload16(bSrc + (size_t)(t * 8) * K + kt * 64, &Bs[wid * 32 + t * 8][0]);
    }
    __syncthreads();
#pragma unroll
    for (int kk = 0; kk < 2; ++kk) {
      bf16x8 af[4], bfr[4];
#pragma unroll
      for (int mi = 0; mi < 4; ++mi)
        af[mi] = *(const bf16x8*)&As[wm + mi * 16 + lr][kk * 32 + lk * 8];
#pragma unroll
      for (int ni = 0; ni < 4; ++ni)
        bfr[ni] = *(const bf16x8*)&Bs[wn + ni * 16 + lr][kk * 32 + lk * 8];
#pragma unroll
      for (int mi = 0; mi < 4; ++mi)
#pragma unroll
        for (int ni = 0; ni < 4; ++ni)
          acc[mi][ni] =
              __builtin_amdgcn_mfma_f32_16x16x32_bf16(af[mi], bfr[ni], acc[mi][ni], 0, 0, 0);
    }
    __syncthreads();
  }

  int row0 = tm * 128 + wm + lk * 4;
  int col0 = tn * 128 + wn + lr;
#pragma unroll
  for (int mi = 0; mi < 4; ++mi) {
    if (MODE == 2) {
#pragma unroll
      for (int ni = 0; ni < 4; ni += 2) {
        int colE = col0 + ni * 16;
        int hidx = ((colE >> 5) << 4) + lr;
        float b1v = cbias[hidx];
        float b2v = cbias[1536 + hidx];
#pragma unroll
        for (int reg = 0; reg < 4; ++reg) {
          int row = row0 + mi * 16 + reg;
          float x1 = acc[mi][ni][reg] + b1v;
          float x2 = acc[mi][ni + 1][reg] + b2v;
          float hv = x1 * x2 / (1.f + __expf(-x2));
          outB[(size_t)row * 1536 + hidx] = f2bf(hv);
        }
      }
    } else if (MODE == 0) {
#pragma unroll
      for (int ni = 0; ni < 4; ++ni) {
        int col = col0 + ni * 16;
        float bv = cbias[col];
        float vals[4];
#pragma unroll
        for (int reg = 0; reg < 4; ++reg) vals[reg] = acc[mi][ni][reg] + bv;
        if (col < 768) {
#pragma unroll
          for (int reg = 0; reg < 4; ++reg)
            outB[(size_t)(row0 + mi * 16 + reg) * 768 + col] = f2bf(vals[reg]);
        } else {
          int head = (col >> 5) - 24, d = col & 31;
          int row = row0 + mi * 16;
          int win = row >> 6, n0 = row & 63;
          uint2 p;
          p.x = (unsigned)f2bf(vals[0]) | ((unsigned)f2bf(vals[1]) << 16);
          p.y = (unsigned)f2bf(vals[2]) | ((unsigned)f2bf(vals[3]) << 16);
          *(uint2*)&outB2[((size_t)(head * 2048 + win) * 32 + d) * 64 + n0] = p;
        }
      }
    } else {
#pragma unroll
      for (int ni = 0; ni < 4; ++ni) {
        int col = col0 + ni * 16;
        float bv = cbias[col];
#pragma unroll
        for (int reg = 0; reg < 4; ++reg) {
          int row = row0 + mi * 16 + reg;
          float v = acc[mi][ni][reg] + bv;
          if (MODE == 1) {
            int win = row >> 6, n = row & 63;
            int bb = win >> 6, wd = win & 63;
            int hh = (((wd >> 3) << 3) + (n >> 3) + 4) & 63;
            int ww2 = (((wd & 7) << 3) + (n & 7) + 4) & 63;
            size_t idx = ((size_t)(bb << 12) + hh * 64 + ww2) * 384 + col;
            outF[idx] = v + shortcut[idx];
          } else {  // MODE 3
            size_t idx = (size_t)row * 384 + col;
            outF[idx] = v + outF[idx];
          }
        }
      }
    }
  }
}

// ---------------- attention v2: 1 wave per (win,head), MFMA ----------------
__device__ __forceinline__ int zone6(int wd, int z) {
  int h = ((wd >> 3) << 3) + (z >> 3);
  int w = ((wd & 7) << 3) + (z & 7);
  return (h < 56 ? 0 : (h < 60 ? 1 : 2)) * 3 + (w < 56 ? 0 : (w < 60 ? 1 : 2));
}

__global__ __launch_bounds__(256, 2) void attn2_kernel(
    const unsigned short* __restrict__ qk,   // [131072][768]
    const unsigned short* __restrict__ vt,   // [12][2048][32][64]
    const float* __restrict__ logit_scale,
    const float* __restrict__ biasr,         // [12][64][64]
    unsigned short* __restrict__ outw) {     // [131072][384]
  __shared__ __align__(16) char smem[4 * 8704];
  int wv = threadIdx.x >> 6, lane = threadIdx.x & 63;
  int head = blockIdx.x * 4 + wv;  // grid (3, 2048)
  int win = blockIdx.y;
  char* Pb = smem + wv * 8704;
  int li = lane & 15, lg = lane >> 4;

  // ---- load Q,K fragments (A/B layout: lane holds X[li+16f][lg*8..+7]) ----
  const unsigned short* qbase = qk + (size_t)(win * 64) * 768 + head * 32 + lg * 8;
  uint4 qf[4], kf[4];
#pragma unroll
  for (int f = 0; f < 4; ++f) {
    qf[f] = *(const uint4*)(qbase + (size_t)(li + 16 * f) * 768);
    kf[f] = *(const uint4*)(qbase + 384 + (size_t)(li + 16 * f) * 768);
  }
  const unsigned short* vbase = vt + (size_t)(head * 2048 + win) * 2048;
  uint4 vf[2][2];
#pragma unroll
  for (int fm = 0; fm < 2; ++fm)
#pragma unroll
    for (int fk = 0; fk < 2; ++fk)
      vf[fm][fk] = *(const uint4*)(vbase + (size_t)(li + 16 * fm) * 64 + lg * 8 + 32 * fk);

  // ---- row norms (over bf16 values) ----
  float rq[4], rk[4];
#pragma unroll
  for (int f = 0; f < 4; ++f) {
    unsigned int aq[4] = {qf[f].x, qf[f].y, qf[f].z, qf[f].w};
    unsigned int ak[4] = {kf[f].x, kf[f].y, kf[f].z, kf[f].w};
    float sq = 0.f, sk = 0.f;
#pragma unroll
    for (int e = 0; e < 4; ++e) {
      float lo = bf2f(aq[e] & 0xffffu), hi = bf2f(aq[e] >> 16);
      sq = fmaf(lo, lo, sq);
      sq = fmaf(hi, hi, sq);
      lo = bf2f(ak[e] & 0xffffu);
      hi = bf2f(ak[e] >> 16);
      sk = fmaf(lo, lo, sk);
      sk = fmaf(hi, hi, sk);
    }
    sq += __shfl_xor(sq, 16);
    sq += __shfl_xor(sq, 32);
    sk += __shfl_xor(sk, 16);
    sk += __shfl_xor(sk, 32);
    rq[f] = 1.f / fmaxf(sqrtf(sq), 1e-12f);
    rk[f] = 1.f / fmaxf(sqrtf(sk), 1e-12f);
  }

  // ---- S^T = K * Q^T : accS[fm(j)][fn(i)], lane: j=lg*4+r+16fm, i=li+16fn ----
  f32x4 accS[4][4];
#pragma unroll
  for (int fm = 0; fm < 4; ++fm)
#pragma unroll
    for (int fn = 0; fn < 4; ++fn) accS[fm][fn] = (f32x4){0.f, 0.f, 0.f, 0.f};
#pragma unroll
  for (int fm = 0; fm < 4; ++fm)
#pragma unroll
    for (int fn = 0; fn < 4; ++fn)
      accS[fm][fn] =
          __builtin_amdgcn_mfma_f32_16x16x32_bf16(as_bf(kf[fm]), as_bf(qf[fn]), accS[fm][fn], 0, 0, 0);

  // ---- redistribute k-norms to S^T row (j) positions via bpermute ----
  float ls = __expf(fminf(logit_scale[head], 4.6051702f));
  float qsc[4];
#pragma unroll
  for (int fn = 0; fn < 4; ++fn) qsc[fn] = ls * rq[fn];
  f32x4 rkv[4];
#pragma unroll
  for (int fm = 0; fm < 4; ++fm)
#pragma unroll
    for (int r = 0; r < 4; ++r)
      rkv[fm][r] = __int_as_float(
          __builtin_amdgcn_ds_bpermute((lg * 4 + r) << 2, __float_as_int(rk[fm])));

  // ---- scale + bias + mask ----
  int wd = win & 63;
  int regi[4];
#pragma unroll
  for (int fn = 0; fn < 4; ++fn) regi[fn] = zone6(wd, li + 16 * fn);
  const float* bb = biasr + ((size_t)(head * 64 + lane)) * 64;
  float mx[4] = {-3e38f, -3e38f, -3e38f, -3e38f};
#pragma unroll
  for (int fm = 0; fm < 4; ++fm) {
    int j0 = lg * 4 + 16 * fm;
    int regj[4];
#pragma unroll
    for (int r = 0; r < 4; ++r) regj[r] = zone6(wd, j0 + r);
#pragma unroll
    for (int fn = 0; fn < 4; ++fn) {
      f32x4 bv = *(const f32x4*)(bb + fn * 16 + fm * 4);
#pragma unroll
      for (int r = 0; r < 4; ++r) {
        float val = accS[fm][fn][r] * (qsc[fn] * rkv[fm][r]);
        val += (regj[r] == regi[fn]) ? bv[r] : -1e30f;
        accS[fm][fn][r] = val;
        mx[fn] = fmaxf(mx[fn], val);
      }
    }
  }

  // ---- softmax over j (per i-column) ----
  float inv[4];
#pragma unroll
  for (int fn = 0; fn < 4; ++fn) {
    float m = mx[fn];
    m = fmaxf(m, __shfl_xor(m, 16));
    m = fmaxf(m, __shfl_xor(m, 32));
    float sum = 0.f;
#pragma unroll
    for (int fm = 0; fm < 4; ++fm)
#pragma unroll
      for (int r = 0; r < 4; ++r) {
        float e = __expf(accS[fm][fn][r] - m);
        accS[fm][fn][r] = e;
        sum += e;
      }
    sum += __shfl_xor(sum, 16);
    sum += __shfl_xor(sum, 32);
    inv[fn] = 1.f / sum;
  }

  // ---- pack P (row i, cols j) into lane-major LDS [64 lanes][136B] ----
#pragma unroll
  for (int fm = 0; fm < 4; ++fm)
#pragma unroll
    for (int fn = 0; fn < 4; ++fn) {
      uint2 p;
      p.x = (unsigned)f2bf(accS[fm][fn][0] * inv[fn]) |
            ((unsigned)f2bf(accS[fm][fn][1] * inv[fn]) << 16);
      p.y = (unsigned)f2bf(accS[fm][fn][2] * inv[fn]) |
            ((unsigned)f2bf(accS[fm][fn][3] * inv[fn]) << 16);
      *(uint2*)(Pb + lane * 136 + fm * 32 + fn * 8) = p;
    }

  // ---- O^T = V^T * P^T : accO[fm(d)][fn(i)] ----
  f32x4 accO[2][4];
#pragma unroll
  for (int fm = 0; fm < 2; ++fm)
#pragma unroll
    for (int fn = 0; fn < 4; ++fn) accO[fm][fn] = (f32x4){0.f, 0.f, 0.f, 0.f};

#pragma unroll
  for (int fk = 0; fk < 2; ++fk) {
    bf16x8 pf[4];
#pragma unroll
    for (int fn = 0; fn < 4; ++fn) {
      int s0 = (li + 16 * ((2 * lg) & 3)) * 136 + (2 * fk + (lg >> 1)) * 32 + fn * 8;
      int s1 = (li + 16 * ((2 * lg + 1) & 3)) * 136 + (2 * fk + (lg >> 1)) * 32 + fn * 8;
      uint2 x0 = *(const uint2*)(Pb + s0);
      uint2 x1 = *(const uint2*)(Pb + s1);
      uint4 comb = {x0.x, x0.y, x1.x, x1.y};
      pf[fn] = as_bf(comb);
    }
#pragma unroll
    for (int fm = 0; fm < 2; ++fm)
#pragma unroll
      for (int fn = 0; fn < 4; ++fn)
        accO[fm][fn] =
            __builtin_amdgcn_mfma_f32_16x16x32_bf16(as_bf(vf[fm][fk]), pf[fn], accO[fm][fn], 0, 0, 0);
  }

  // ---- store O: lane holds O^T[d=lg*4+r+16fm][i=li+16fn] ----
#pragma unroll
  for (int fm = 0; fm < 2; ++fm)
#pragma unroll
    for (int fn = 0; fn < 4; ++fn) {
      uint2 p;
      p.x = (unsigned)f2bf(accO[fm][fn][0]) | ((unsigned)f2bf(accO[fm][fn][1]) << 16);
      p.y = (unsigned)f2bf(accO[fm][fn][2]) | ((unsigned)f2bf(accO[fm][fn][3]) << 16);
      *(uint2*)&outw[(size_t)(win * 64 + li + 16 * fn) * 384 + head * 32 + lg * 4 + 16 * fm] = p;
    }
}

// ---------------------------------------------------------------------------

extern "C" void kernel_launch(void* const* d_in, const int* in_sizes, int n_in,
                              void* d_out, int out_size, void* d_ws, size_t ws_size,
                              hipStream_t stream) {
  const float* x = (const float*)d_in[0];
  const float* n1g = (const float*)d_in[3];
  const float* n1b = (const float*)d_in[4];
  const float* qkv_w = (const float*)d_in[5];
  const float* qkv_b = (const float*)d_in[6];
  const float* proj_w = (const float*)d_in[7];
  const float* proj_b = (const float*)d_in[8];
  const float* cpb_w1 = (const float*)d_in[9];
  const float* cpb_b1 = (const float*)d_in[10];
  const float* cpb_w2 = (const float*)d_in[11];
  const float* lscale = (const float*)d_in[12];
  const float* n2g = (const float*)d_in[13];
  const float* n2b = (const float*)d_in[14];
  const float* w12_w = (const float*)d_in[15];
  const float* w12_b = (const float*)d_in[16];
  const float* w3_w = (const float*)d_in[17];
  const float* w3_b = (const float*)d_in[18];
  float* outF = (float*)d_out;
  char* ws = (char*)d_ws;

  // workspace layout (bytes)
  unsigned short* xw = (unsigned short*)(ws + 0ull);            // 100663296  [0,100M)
  unsigned short* qkb = (unsigned short*)(ws + 100663296ull);   // 201326592  [100M,302M)
  unsigned short* vtb = (unsigned short*)(ws + 301989888ull);   // 100663296  [302M,402M)
  unsigned short* attnout = (unsigned short*)(ws + 0ull);       // reuse xw
  unsigned short* xn2 = (unsigned short*)(ws + 402653184ull);   // 100663296  [402M,503M)
  unsigned short* hbuf = (unsigned short*)(ws + 0ull);          // 402653184  [0,402M)
  char* wbase = ws + 503316480ull;
  unsigned short* wqkv = (unsigned short*)(wbase);               // 884736
  unsigned short* wproj = (unsigned short*)(wbase + 884736ull);  // 294912
  unsigned short* w12r = (unsigned short*)(wbase + 1179648ull);  // 2359296
  unsigned short* w3b = (unsigned short*)(wbase + 3538944ull);   // 1179648
  float* tbl = (float*)(wbase + 4718592ull);                     // 10816
  float* biasr = (float*)(wbase + 4729408ull);                   // 196608

  cvt_bf16_kernel<<<1728, 256, 0, stream>>>(qkv_w, wqkv, 442368);
  cvt_bf16_kernel<<<576, 256, 0, stream>>>(proj_w, wproj, 147456);
  cvt_bf16_kernel<<<2304, 256, 0, stream>>>(w3_w, w3b, 589824);
  w12_reorder_kernel<<<4608, 256, 0, stream>>>(w12_w, w12r);
  cpb_table_kernel<<<1, 256, 0, stream>>>(cpb_w1, cpb_b1, cpb_w2, tbl);
  bias_fill_kernel<<<192, 256, 0, stream>>>(tbl, biasr);

  ln_kernel<<<32768, 256, 0, stream>>>(x, n1g, n1b, xw, 1);
  gemm_bt<0><<<dim3(9, 1024), 256, 0, stream>>>(xw, wqkv, qkv_b, qkb, vtb, nullptr,
                                                nullptr, 1152, 384);
  attn2_kernel<<<dim3(3, 2048), 256, 0, stream>>>(qkb, vtb, lscale, biasr, attnout);
  gemm_bt<1><<<dim3(3, 1024), 256, 0, stream>>>(attnout, wproj, proj_b, nullptr, nullptr,
                                                outF, x, 384, 384);
  ln_kernel<<<32768, 256, 0, stream>>>(outF, n2g, n2b, xn2, 0);
  gemm_bt<2><<<dim3(24, 1024), 256, 0, stream>>>(xn2, w12r, w12_b, hbuf, nullptr, nullptr,
                                                 nullptr, 3072, 384);
  gemm_bt<3><<<dim3(3, 1024), 256, 0, stream>>>(hbuf, w3b, w3_b, nullptr, nullptr, outF,
                                                nullptr, 384, 1536);
}